// Round 5
// baseline (4031.083 us; speedup 1.0000x reference)
//
#include <hip/hip_runtime.h>
#include <cstdint>
#include <cstddef>

typedef __attribute__((ext_vector_type(8))) short short8;
typedef __attribute__((ext_vector_type(4))) short short4v;
typedef __attribute__((ext_vector_type(4))) float f32x4;

static constexpr int B_ = 64, T_ = 256, D_ = 1024, NH = 1024, NG = 4096;
static constexpr int NBLK = 128;   // recurrence blocks, 8 units each
static constexpr int LDS_BYTES = 65536 + 65536 + 8448 + 2048;  // UsH,UsL,zsm(pad33),csm

__device__ __forceinline__ short f2bs(float f) {
  union { float f; uint32_t u; } cv; cv.f = f;
  uint32_t u = cv.u;
  uint32_t r = (u + 0x7fffu + ((u >> 16) & 1u)) >> 16;  // RNE
  return (short)(uint16_t)r;
}
__device__ __forceinline__ float bs2f(short s) {
  union { uint32_t u; float f; } cv; cv.u = ((uint32_t)(uint16_t)s) << 16; return cv.f;
}
__device__ __forceinline__ float fsigm(float x) {
  return __builtin_amdgcn_rcpf(1.f + __expf(-x));
}
__device__ __forceinline__ float ftanh(float x) {
  return 1.f - 2.f * __builtin_amdgcn_rcpf(__expf(2.f * x) + 1.f);
}

// ---------------------------------------------------------------------------
// xz = x @ W + bias  (M=16384,K=1024,N=4096), bf16, scattered step-major:
// xzT[((ublk*256 + t)*64 + b)*32 + uj*4 + g]   (ublk=u>>3, uj=u&7, g=gate)
// ---------------------------------------------------------------------------
__global__ __launch_bounds__(256) void xz_gemm(const float* __restrict__ x,
                                               const float* __restrict__ W,
                                               const float* __restrict__ bias,
                                               short* __restrict__ xzT)
{
  constexpr int BM = 128, BN = 128, BK = 32;
  __shared__ short As[BM][BK];
  __shared__ short Bs[BK][BN];
  const int tid  = threadIdx.x;
  const int lane = tid & 63, wave = tid >> 6;
  const int wm = (wave >> 1) * 64, wn = (wave & 1) * 64;
  const int fr = lane & 15, kg = lane >> 4;
  const int bm = blockIdx.x * BM, bn = blockIdx.y * BN;

  f32x4 acc[4][4] = {};

  for (int k0 = 0; k0 < D_; k0 += BK) {
    {
      const int r0 = tid >> 3, kq = (tid & 7) * 4;
      #pragma unroll
      for (int it = 0; it < 4; ++it) {
        const int row = r0 + it * 32;
        const float4 v = *reinterpret_cast<const float4*>(&x[(size_t)(bm + row) * D_ + k0 + kq]);
        short4v s; s.x = f2bs(v.x); s.y = f2bs(v.y); s.z = f2bs(v.z); s.w = f2bs(v.w);
        *reinterpret_cast<short4v*>(&As[row][kq]) = s;
      }
    }
    {
      const int kr0 = tid >> 5, nq = (tid & 31) * 4;
      #pragma unroll
      for (int it = 0; it < 4; ++it) {
        const int krow = kr0 + it * 8;
        const float4 v = *reinterpret_cast<const float4*>(&W[(size_t)(k0 + krow) * NG + bn + nq]);
        short4v s; s.x = f2bs(v.x); s.y = f2bs(v.y); s.z = f2bs(v.z); s.w = f2bs(v.w);
        *reinterpret_cast<short4v*>(&Bs[krow][nq]) = s;
      }
    }
    __syncthreads();

    short8 af[4];
    #pragma unroll
    for (int mi = 0; mi < 4; ++mi)
      af[mi] = *reinterpret_cast<const short8*>(&As[wm + mi * 16 + fr][kg * 8]);
    #pragma unroll
    for (int ni = 0; ni < 4; ++ni) {
      short8 bf;
      #pragma unroll
      for (int j = 0; j < 8; ++j) bf[j] = Bs[kg * 8 + j][wn + ni * 16 + fr];
      #pragma unroll
      for (int mi = 0; mi < 4; ++mi)
        acc[mi][ni] = __builtin_amdgcn_mfma_f32_16x16x32_bf16(af[mi], bf, acc[mi][ni], 0, 0, 0);
    }
    __syncthreads();
  }

  const int fq = lane >> 4;
  #pragma unroll
  for (int ni = 0; ni < 4; ++ni) {
    const int col = bn + wn + ni * 16 + fr;
    const int g = col >> 10, u = col & 1023;
    const int ublk = u >> 3, uj = u & 7;
    const float bv = bias[col];
    #pragma unroll
    for (int mi = 0; mi < 4; ++mi) {
      const int rowb = bm + wm + mi * 16 + fq * 4;
      #pragma unroll
      for (int r = 0; r < 4; ++r) {
        const int row = rowb + r;
        const int b = row >> 8, t = row & 255;
        xzT[((size_t)(ublk * 256 + t) * 64 + b) * 32 + uj * 4 + g] = f2bs(acc[mi][ni][r] + bv);
      }
    }
  }
}

// ---------------------------------------------------------------------------
// Persistent recurrence, fence-free cross-XCD coherence:
//  - h stores:  global_store_dword sc0 sc1 (write-through) + vmcnt drain
//  - h loads:   global_load_dwordx4 sc0 sc1 (read-around stale caches)
//  - signal:    4 per-step group counters (64B-padded), one relaxed-agent
//               atomic_add per block; consumers poll with lane==0 only.
// 128 blocks x 512 thr; block owns 8 units (32 gate cols); U hi/lo in LDS.
// ---------------------------------------------------------------------------
#define H_ISSUE(BUF, O0,O1,O2,O3,O4,O5,O6,O7) \
  asm volatile( \
    "global_load_dwordx4 %0, %8, off offset:" #O0 " sc0 sc1\n\t" \
    "global_load_dwordx4 %1, %8, off offset:" #O1 " sc0 sc1\n\t" \
    "global_load_dwordx4 %2, %8, off offset:" #O2 " sc0 sc1\n\t" \
    "global_load_dwordx4 %3, %8, off offset:" #O3 " sc0 sc1\n\t" \
    "global_load_dwordx4 %4, %8, off offset:" #O4 " sc0 sc1\n\t" \
    "global_load_dwordx4 %5, %8, off offset:" #O5 " sc0 sc1\n\t" \
    "global_load_dwordx4 %6, %8, off offset:" #O6 " sc0 sc1" \
    "\n\tglobal_load_dwordx4 %7, %8, off offset:" #O7 " sc0 sc1" \
    : "=&v"(BUF[0]), "=&v"(BUF[1]), "=&v"(BUF[2]), "=&v"(BUF[3]), \
      "=&v"(BUF[4]), "=&v"(BUF[5]), "=&v"(BUF[6]), "=&v"(BUF[7]) \
    : "v"(hp) : "memory")

#define WAITV(N) do { asm volatile("s_waitcnt vmcnt(" #N ")" ::: "memory"); \
                      __builtin_amdgcn_sched_barrier(0); } while (0)

// chunk C (k in [256C, 256C+256)) is produced by blocks [32C, 32C+32)
#define POLL_GROUP(C) \
  if (lane == 0) { \
    const int* cp = counters + (((t - 1) * 4 + (C)) * 16); \
    while (__hip_atomic_load(cp, __ATOMIC_RELAXED, __HIP_MEMORY_SCOPE_AGENT) < 32) \
      __builtin_amdgcn_s_sleep(1); \
  }

#define MFMA_CHUNK(BUF, C) \
  { _Pragma("unroll") \
    for (int i = 0; i < 8; ++i) { \
      const int so = ((C) * 8 + i) * 1024 + kg * 256 + cc8; \
      const short8 bh = *reinterpret_cast<const short8*>(&UsH[so]); \
      const short8 bl = *reinterpret_cast<const short8*>(&UsL[so]); \
      acc = __builtin_amdgcn_mfma_f32_16x16x32_bf16(BUF[i], bh, acc, 0, 0, 0); \
      acc = __builtin_amdgcn_mfma_f32_16x16x32_bf16(BUF[i], bl, acc, 0, 0, 0); \
    } }

__global__ __launch_bounds__(512) void lstm_persist(const short* __restrict__ xzT,
                                                    const float* __restrict__ U,
                                                    short* __restrict__ h0buf,
                                                    short* __restrict__ h1buf,
                                                    int* __restrict__ counters,
                                                    float* __restrict__ out)
{
  extern __shared__ char smem[];
  short* UsH = (short*)smem;                       // [kb][c][k&7] 64 KiB
  short* UsL = (short*)(smem + 65536);             // 64 KiB
  float* zsm = (float*)(smem + 131072);            // [64][33]
  float* csm = (float*)(smem + 131072 + 8448);     // [64][8]

  const int tid  = threadIdx.x;
  const int lane = tid & 63, wave = tid >> 6;
  const int bid  = blockIdx.x;
  const int u0   = bid * 8;
  const int fr = lane & 15, kg = lane >> 4;
  const int mt = wave & 3;      // batch tile (16 rows)
  const int nt = wave >> 2;     // col tile (16 of 32 cols)
  const int cc8 = (nt * 16 + fr) * 8;
  const int gb = tid >> 3, guj = tid & 7;  // gate-math mapping

  // Stage U slice once (hi/lo bf16 split ~= fp32 accuracy).
  for (int idx = tid; idx < 1024 * 32; idx += 512) {
    const int k = idx >> 5, c = idx & 31;
    const int g = c >> 3, uj = c & 7;
    const float v = U[(size_t)k * NG + g * NH + u0 + uj];
    const short hi = f2bs(v);
    const short lo = f2bs(v - bs2f(hi));
    const int off = ((k >> 3) * 32 + c) * 8 + (k & 7);
    UsH[off] = hi; UsL[off] = lo;
  }
  csm[tid] = 0.f;
  __syncthreads();

  for (int t = 0; t < T_; ++t) {
    const short* __restrict__ hprev = (t & 1) ? h0buf : h1buf;
    short* __restrict__ hnext       = (t & 1) ? h1buf : h0buf;

    // Step's xz for this thread: 4 contiguous bf16 (one 8B load).
    const short4v xzv = *reinterpret_cast<const short4v*>(
        &xzT[(((size_t)bid * 256 + t) * 64 + gb) * 32 + guj * 4]);

    if (t > 0) {
      f32x4 acc = {0.f, 0.f, 0.f, 0.f};
      const short* hp = hprev + (size_t)(mt * 16 + fr) * NH + kg * 8;
      short8 ha[8], hb[8];
      POLL_GROUP(0); H_ISSUE(ha, 0, 64, 128, 192, 256, 320, 384, 448);
      POLL_GROUP(1); H_ISSUE(hb, 512, 576, 640, 704, 768, 832, 896, 960);
      WAITV(8);  MFMA_CHUNK(ha, 0);
      POLL_GROUP(2); H_ISSUE(ha, 1024, 1088, 1152, 1216, 1280, 1344, 1408, 1472);
      WAITV(8);  MFMA_CHUNK(hb, 1);
      POLL_GROUP(3); H_ISSUE(hb, 1536, 1600, 1664, 1728, 1792, 1856, 1920, 1984);
      WAITV(8);  MFMA_CHUNK(ha, 2);
      WAITV(0);  MFMA_CHUNK(hb, 3);
      // C/D: col = lane&15, row = (lane>>4)*4 + r
      #pragma unroll
      for (int r = 0; r < 4; ++r)
        zsm[(mt * 16 + kg * 4 + r) * 33 + nt * 16 + fr] = acc[r];
    }
    __syncthreads();

    float hh;
    {  // gate math: thread = (b=gb, uj=guj)
      const float zi = bs2f(xzv[0]) + ((t > 0) ? zsm[gb * 33 + guj]      : 0.f);
      const float zf = bs2f(xzv[1]) + ((t > 0) ? zsm[gb * 33 + 8 + guj]  : 0.f);
      const float zg = bs2f(xzv[2]) + ((t > 0) ? zsm[gb * 33 + 16 + guj] : 0.f);
      const float zo = bs2f(xzv[3]) + ((t > 0) ? zsm[gb * 33 + 24 + guj] : 0.f);
      const float ig = fsigm(zi);
      const float fg = fsigm(zf);
      const float gg = ftanh(zg);
      const float og = fsigm(zo);
      const float cc = fg * csm[tid] + ig * gg;
      hh = og * ftanh(cc);
      csm[tid] = cc;

      // h store: pack 2 bf16 -> u32, write-through sc0 sc1
      const short hb16 = f2bs(hh);
      const int partner = __shfl_xor((int)(uint16_t)hb16, 1);
      if (!(lane & 1)) {
        const uint32_t word = (uint32_t)(uint16_t)hb16 | ((uint32_t)partner << 16);
        uint32_t* hp32 = (uint32_t*)(hnext + (size_t)gb * NH + u0 + guj);
        asm volatile("global_store_dword %0, %1, off sc0 sc1" :: "v"(hp32), "v"(word) : "memory");
      }
      asm volatile("s_waitcnt vmcnt(0)" ::: "memory");
      __builtin_amdgcn_sched_barrier(0);
    }
    __syncthreads();   // all waves' h stores drained & globally visible

    if (t < T_ - 1 && tid == 0)
      __hip_atomic_fetch_add(&counters[(t * 4 + (bid >> 5)) * 16], 1,
                             __ATOMIC_RELAXED, __HIP_MEMORY_SCOPE_AGENT);

    // out store off the signal critical path
    out[((size_t)gb * T_ + t) * NH + u0 + guj] = hh;
  }
}

extern "C" void kernel_launch(void* const* d_in, const int* in_sizes, int n_in,
                              void* d_out, int out_size, void* d_ws, size_t ws_size,
                              hipStream_t stream) {
  const float* x    = (const float*)d_in[0];
  const float* W    = (const float*)d_in[1];
  const float* U    = (const float*)d_in[2];
  const float* bias = (const float*)d_in[3];
  float* out = (float*)d_out;
  char* ws = (char*)d_ws;

  // ws: xzT bf16 128 MiB | counters 64 KiB | h ping/pong 2 x 128 KiB
  short* xzT      = (short*)ws;
  int*   counters = (int*)(ws + 134217728);
  short* hA       = (short*)(ws + 134283264);
  short* hB       = (short*)(ws + 134414336);

  hipMemsetAsync(counters, 0, 65536, stream);
  xz_gemm<<<dim3(128, 32), 256, 0, stream>>>(x, W, bias, xzT);

  hipFuncSetAttribute((const void*)lstm_persist,
                      hipFuncAttributeMaxDynamicSharedMemorySize, LDS_BYTES);
  lstm_persist<<<dim3(NBLK), dim3(512), LDS_BYTES, stream>>>(xzT, U, hA, hB, counters, out);
}

// Round 7
// 2921.560 us; speedup vs baseline: 1.3798x; 1.3798x over previous
//
#include <hip/hip_runtime.h>
#include <cstdint>
#include <cstddef>

typedef __attribute__((ext_vector_type(8))) short short8;
typedef __attribute__((ext_vector_type(4))) short short4v;
typedef __attribute__((ext_vector_type(4))) float f32x4;

static constexpr int B_ = 64, T_ = 256, D_ = 1024, NH = 1024, NG = 4096;
static constexpr int NBLK = 128;   // recurrence blocks, 8 units each
// UsH 64K | UsL 64K | zsm 8448 | csm 2048 | go 256
static constexpr int LDS_BYTES = 65536 + 65536 + 8448 + 2048 + 256;

__device__ __forceinline__ short f2bs(float f) {
  union { float f; uint32_t u; } cv; cv.f = f;
  uint32_t u = cv.u;
  uint32_t r = (u + 0x7fffu + ((u >> 16) & 1u)) >> 16;  // RNE
  return (short)(uint16_t)r;
}
__device__ __forceinline__ float bs2f(short s) {
  union { uint32_t u; float f; } cv; cv.u = ((uint32_t)(uint16_t)s) << 16; return cv.f;
}
__device__ __forceinline__ float fsigm(float x) {
  return __builtin_amdgcn_rcpf(1.f + __expf(-x));
}
__device__ __forceinline__ float ftanh(float x) {
  return 1.f - 2.f * __builtin_amdgcn_rcpf(__expf(2.f * x) + 1.f);
}

// ---------------------------------------------------------------------------
// xz = x @ W + bias  (M=16384,K=1024,N=4096), bf16, scattered step-major:
// xzT[((ublk*256 + t)*64 + b)*32 + uj*4 + g]   (ublk=u>>3, uj=u&7, g=gate)
// ---------------------------------------------------------------------------
__global__ __launch_bounds__(256) void xz_gemm(const float* __restrict__ x,
                                               const float* __restrict__ W,
                                               const float* __restrict__ bias,
                                               short* __restrict__ xzT)
{
  constexpr int BM = 128, BN = 128, BK = 32;
  __shared__ short As[BM][BK];
  __shared__ short Bs[BK][BN];
  const int tid  = threadIdx.x;
  const int lane = tid & 63, wave = tid >> 6;
  const int wm = (wave >> 1) * 64, wn = (wave & 1) * 64;
  const int fr = lane & 15, kg = lane >> 4;
  const int bm = blockIdx.x * BM, bn = blockIdx.y * BN;

  f32x4 acc[4][4] = {};

  for (int k0 = 0; k0 < D_; k0 += BK) {
    {
      const int r0 = tid >> 3, kq = (tid & 7) * 4;
      #pragma unroll
      for (int it = 0; it < 4; ++it) {
        const int row = r0 + it * 32;
        const float4 v = *reinterpret_cast<const float4*>(&x[(size_t)(bm + row) * D_ + k0 + kq]);
        short4v s; s.x = f2bs(v.x); s.y = f2bs(v.y); s.z = f2bs(v.z); s.w = f2bs(v.w);
        *reinterpret_cast<short4v*>(&As[row][kq]) = s;
      }
    }
    {
      const int kr0 = tid >> 5, nq = (tid & 31) * 4;
      #pragma unroll
      for (int it = 0; it < 4; ++it) {
        const int krow = kr0 + it * 8;
        const float4 v = *reinterpret_cast<const float4*>(&W[(size_t)(k0 + krow) * NG + bn + nq]);
        short4v s; s.x = f2bs(v.x); s.y = f2bs(v.y); s.z = f2bs(v.z); s.w = f2bs(v.w);
        *reinterpret_cast<short4v*>(&Bs[krow][nq]) = s;
      }
    }
    __syncthreads();

    short8 af[4];
    #pragma unroll
    for (int mi = 0; mi < 4; ++mi)
      af[mi] = *reinterpret_cast<const short8*>(&As[wm + mi * 16 + fr][kg * 8]);
    #pragma unroll
    for (int ni = 0; ni < 4; ++ni) {
      short8 bf;
      #pragma unroll
      for (int j = 0; j < 8; ++j) bf[j] = Bs[kg * 8 + j][wn + ni * 16 + fr];
      #pragma unroll
      for (int mi = 0; mi < 4; ++mi)
        acc[mi][ni] = __builtin_amdgcn_mfma_f32_16x16x32_bf16(af[mi], bf, acc[mi][ni], 0, 0, 0);
    }
    __syncthreads();
  }

  const int fq = lane >> 4;
  #pragma unroll
  for (int ni = 0; ni < 4; ++ni) {
    const int col = bn + wn + ni * 16 + fr;
    const int g = col >> 10, u = col & 1023;
    const int ublk = u >> 3, uj = u & 7;
    const float bv = bias[col];
    #pragma unroll
    for (int mi = 0; mi < 4; ++mi) {
      const int rowb = bm + wm + mi * 16 + fq * 4;
      #pragma unroll
      for (int r = 0; r < 4; ++r) {
        const int row = rowb + r;
        const int b = row >> 8, t = row & 255;
        xzT[((size_t)(ublk * 256 + t) * 64 + b) * 32 + uj * 4 + g] = f2bs(acc[mi][ni][r] + bv);
      }
    }
  }
}

// ---------------------------------------------------------------------------
// Persistent recurrence, fence-free cross-XCD coherence.
//  - h stores:  global_store_dword sc0 sc1 (write-through) + vmcnt drain
//  - h loads:   global_load_dwordx4 sc0 sc1 (MALL-direct)
//  - signal:    producer stores flags[bid] = t+1 after step t's h drain
//               ("h(t) visible"). ONLY wave 8 polls global flags; it
//               publishes per-chunk readiness via LDS go[]. MFMA waves
//               spin on LDS (lgkmcnt domain) so the counted vmcnt(8)
//               h-load pipeline is never drained by polling.
// 128 blocks x 576 thr (8 MFMA waves + 1 signal wave); block owns 8 units.
// ---------------------------------------------------------------------------
#define H_ISSUE(BUF, O0,O1,O2,O3,O4,O5,O6,O7) \
  asm volatile( \
    "global_load_dwordx4 %0, %8, off offset:" #O0 " sc0 sc1\n\t" \
    "global_load_dwordx4 %1, %8, off offset:" #O1 " sc0 sc1\n\t" \
    "global_load_dwordx4 %2, %8, off offset:" #O2 " sc0 sc1\n\t" \
    "global_load_dwordx4 %3, %8, off offset:" #O3 " sc0 sc1\n\t" \
    "global_load_dwordx4 %4, %8, off offset:" #O4 " sc0 sc1\n\t" \
    "global_load_dwordx4 %5, %8, off offset:" #O5 " sc0 sc1\n\t" \
    "global_load_dwordx4 %6, %8, off offset:" #O6 " sc0 sc1" \
    "\n\tglobal_load_dwordx4 %7, %8, off offset:" #O7 " sc0 sc1" \
    : "=&v"(BUF[0]), "=&v"(BUF[1]), "=&v"(BUF[2]), "=&v"(BUF[3]), \
      "=&v"(BUF[4]), "=&v"(BUF[5]), "=&v"(BUF[6]), "=&v"(BUF[7]) \
    : "v"(hp) : "memory")

#define WAITV(N) do { asm volatile("s_waitcnt vmcnt(" #N ")" ::: "memory"); \
                      __builtin_amdgcn_sched_barrier(0); } while (0)

// MFMA waves wait on LDS-published readiness (lgkmcnt domain only).
#define LDSWAIT(C) do { \
    while (__hip_atomic_load(&go[C], __ATOMIC_RELAXED, __HIP_MEMORY_SCOPE_WORKGROUP) < t) \
      __builtin_amdgcn_s_sleep(1); \
    __builtin_amdgcn_sched_barrier(0); \
  } while (0)

#define MFMA_CHUNK(BUF, C) \
  { _Pragma("unroll") \
    for (int i = 0; i < 8; ++i) { \
      const int so = ((C) * 8 + i) * 1024 + kg * 256 + cc8; \
      const short8 bh = *reinterpret_cast<const short8*>(&UsH[so]); \
      const short8 bl = *reinterpret_cast<const short8*>(&UsL[so]); \
      acch = __builtin_amdgcn_mfma_f32_16x16x32_bf16(BUF[i], bh, acch, 0, 0, 0); \
      accl = __builtin_amdgcn_mfma_f32_16x16x32_bf16(BUF[i], bl, accl, 0, 0, 0); \
    } }

__global__ __launch_bounds__(576) void lstm_persist(const short* __restrict__ xzT,
                                                    const float* __restrict__ U,
                                                    short* __restrict__ h0buf,
                                                    short* __restrict__ h1buf,
                                                    int* __restrict__ flags,
                                                    float* __restrict__ out)
{
  extern __shared__ char smem[];
  short* UsH = (short*)smem;                             // 64 KiB
  short* UsL = (short*)(smem + 65536);                   // 64 KiB
  float* zsm = (float*)(smem + 131072);                  // [64][33]
  float* csm = (float*)(smem + 131072 + 8448);           // [64][8]
  int*   go  = (int*)(smem + 131072 + 8448 + 2048);      // [4] chunk readiness

  const int tid  = threadIdx.x;
  const int lane = tid & 63, wave = tid >> 6;
  const int bid  = blockIdx.x;
  const int u0   = bid * 8;
  const int fr = lane & 15, kg = lane >> 4;
  const int mt = wave & 3;         // batch tile (16 rows)   [waves 0..7]
  const int nt = (wave >> 2) & 1;  // col tile
  const int cc8 = (nt * 16 + fr) * 8;
  const int gb = tid >> 3, guj = tid & 7;  // gate-math mapping (tid<512)

  // Stage U slice once (hi/lo bf16 split ~= fp32 accuracy).
  for (int idx = tid; idx < 1024 * 32; idx += 576) {
    const int k = idx >> 5, c = idx & 31;
    const int g = c >> 3, uj = c & 7;
    const float v = U[(size_t)k * NG + g * NH + u0 + uj];
    const short hi = f2bs(v);
    const short lo = f2bs(v - bs2f(hi));
    const int off = ((k >> 3) * 32 + c) * 8 + (k & 7);
    UsH[off] = hi; UsL[off] = lo;
  }
  if (tid < 512) csm[tid] = 0.f;
  if (tid < 4)   go[tid] = 0;
  __syncthreads();

  for (int t = 0; t < T_; ++t) {
    const short* __restrict__ hprev = (t & 1) ? h0buf : h1buf;
    short* __restrict__ hnext       = (t & 1) ? h1buf : h0buf;

    short4v xzv = {};
    if (tid < 512)
      xzv = *reinterpret_cast<const short4v*>(
          &xzT[(((size_t)bid * 256 + t) * 64 + gb) * 32 + guj * 4]);

    if (t > 0) {
      if (wave == 8) {
        // Signal wave: poll global flags ("h(t-1) visible" = value >= t),
        // publish chunk readiness to LDS.
        #pragma unroll
        for (int c = 0; c < 4; ++c) {
          if (lane < 32) {
            const int* fp = flags + (c * 32 + lane) * 16;
            while (__hip_atomic_load(fp, __ATOMIC_RELAXED, __HIP_MEMORY_SCOPE_AGENT) < t)
              __builtin_amdgcn_s_sleep(1);
          }
          if (lane == 0)
            __hip_atomic_store(&go[c], t, __ATOMIC_RELAXED, __HIP_MEMORY_SCOPE_WORKGROUP);
        }
      } else {
        f32x4 acch = {0.f, 0.f, 0.f, 0.f}, accl = {0.f, 0.f, 0.f, 0.f};
        const short* hp = hprev + (size_t)(mt * 16 + fr) * NH + kg * 8;
        short8 ha[8], hb[8];
        LDSWAIT(0); H_ISSUE(ha, 0, 64, 128, 192, 256, 320, 384, 448);
        LDSWAIT(1); H_ISSUE(hb, 512, 576, 640, 704, 768, 832, 896, 960);
        WAITV(8);  MFMA_CHUNK(ha, 0);
        LDSWAIT(2); H_ISSUE(ha, 1024, 1088, 1152, 1216, 1280, 1344, 1408, 1472);
        WAITV(8);  MFMA_CHUNK(hb, 1);
        LDSWAIT(3); H_ISSUE(hb, 1536, 1600, 1664, 1728, 1792, 1856, 1920, 1984);
        WAITV(8);  MFMA_CHUNK(ha, 2);
        WAITV(0);  MFMA_CHUNK(hb, 3);
        const f32x4 acc = acch + accl;
        // C/D: col = lane&15, row = (lane>>4)*4 + r
        #pragma unroll
        for (int r = 0; r < 4; ++r)
          zsm[(mt * 16 + kg * 4 + r) * 33 + nt * 16 + fr] = acc[r];
      }
    }
    __syncthreads();

    float hh = 0.f;
    if (tid < 512) {  // gate math: thread = (b=gb, uj=guj)
      const float zi = bs2f(xzv[0]) + ((t > 0) ? zsm[gb * 33 + guj]      : 0.f);
      const float zf = bs2f(xzv[1]) + ((t > 0) ? zsm[gb * 33 + 8 + guj]  : 0.f);
      const float zg = bs2f(xzv[2]) + ((t > 0) ? zsm[gb * 33 + 16 + guj] : 0.f);
      const float zo = bs2f(xzv[3]) + ((t > 0) ? zsm[gb * 33 + 24 + guj] : 0.f);
      const float ig = fsigm(zi);
      const float fg = fsigm(zf);
      const float gg = ftanh(zg);
      const float og = fsigm(zo);
      const float cc = fg * csm[tid] + ig * gg;
      hh = og * ftanh(cc);
      csm[tid] = cc;

      if (t < T_ - 1) {
        // h store: pack 2 bf16 -> u32, write-through sc0 sc1
        const short hb16 = f2bs(hh);
        const int partner = __shfl_xor((int)(uint16_t)hb16, 1);
        if (!(lane & 1)) {
          const uint32_t word = (uint32_t)(uint16_t)hb16 | ((uint32_t)partner << 16);
          uint32_t* hp32 = (uint32_t*)(hnext + (size_t)gb * NH + u0 + guj);
          asm volatile("global_store_dword %0, %1, off sc0 sc1" :: "v"(hp32), "v"(word) : "memory");
        }
      }
    }
    if (t < T_ - 1) {
      asm volatile("s_waitcnt vmcnt(0)" ::: "memory");
      __builtin_amdgcn_sched_barrier(0);
    }
    __syncthreads();   // all h stores drained & globally visible

    if (t < T_ - 1 && tid == 0)
      __hip_atomic_store(&flags[bid * 16], t + 1, __ATOMIC_RELAXED, __HIP_MEMORY_SCOPE_AGENT);

    // out store off the signal critical path (hh is in-register; no LDS reuse)
    if (tid < 512)
      out[((size_t)gb * T_ + t) * NH + u0 + guj] = hh;
  }
}

extern "C" void kernel_launch(void* const* d_in, const int* in_sizes, int n_in,
                              void* d_out, int out_size, void* d_ws, size_t ws_size,
                              hipStream_t stream) {
  const float* x    = (const float*)d_in[0];
  const float* W    = (const float*)d_in[1];
  const float* U    = (const float*)d_in[2];
  const float* bias = (const float*)d_in[3];
  float* out = (float*)d_out;
  char* ws = (char*)d_ws;

  // ws: xzT bf16 128 MiB | flags 8 KiB | h ping/pong 2 x 128 KiB
  short* xzT   = (short*)ws;
  int*   flags = (int*)(ws + 134217728);
  short* hA    = (short*)(ws + 134225920);
  short* hB    = (short*)(ws + 134356992);

  hipMemsetAsync(flags, 0, 8192, stream);  // 0 = "no h visible yet"; blocks t=1 until step-0 stores land
  xz_gemm<<<dim3(128, 32), 256, 0, stream>>>(x, W, bias, xzT);

  hipFuncSetAttribute((const void*)lstm_persist,
                      hipFuncAttributeMaxDynamicSharedMemorySize, LDS_BYTES);
  lstm_persist<<<dim3(NBLK), dim3(512 + 64), LDS_BYTES, stream>>>(xzT, U, hA, hB, flags, out);
}

// Round 8
// 2109.243 us; speedup vs baseline: 1.9112x; 1.3851x over previous
//
#include <hip/hip_runtime.h>
#include <cstdint>
#include <cstddef>

typedef __attribute__((ext_vector_type(8))) short short8;
typedef __attribute__((ext_vector_type(4))) short short4v;
typedef __attribute__((ext_vector_type(4))) float f32x4;

static constexpr int B_ = 64, T_ = 256, D_ = 1024, NH = 1024, NG = 4096;
static constexpr int NBLK = 64;    // recurrence blocks, 16 units each
// Us 128K | zsm 16K | go 64B
static constexpr int LDS_BYTES = 131072 + 16384 + 64;

__device__ __forceinline__ short f2bs(float f) {
  union { float f; uint32_t u; } cv; cv.f = f;
  uint32_t u = cv.u;
  uint32_t r = (u + 0x7fffu + ((u >> 16) & 1u)) >> 16;  // RNE
  return (short)(uint16_t)r;
}
__device__ __forceinline__ float bs2f(short s) {
  union { uint32_t u; float f; } cv; cv.u = ((uint32_t)(uint16_t)s) << 16; return cv.f;
}
__device__ __forceinline__ float fsigm(float x) {
  return __builtin_amdgcn_rcpf(1.f + __expf(-x));
}
__device__ __forceinline__ float ftanh(float x) {
  return 1.f - 2.f * __builtin_amdgcn_rcpf(__expf(2.f * x) + 1.f);
}

// ---------------------------------------------------------------------------
// xz = x @ W + bias  (M=16384,K=1024,N=4096), bf16, step-major layout:
//   xzT[((rb*256 + t)*64 + b)*64 + g*16 + uj]   rb=u>>4, uj=u&15, g=gate
// Epilogue goes through an LDS C-tile so stores are 16B-contiguous.
// ---------------------------------------------------------------------------
__global__ __launch_bounds__(256) void xz_gemm(const float* __restrict__ x,
                                               const float* __restrict__ W,
                                               const float* __restrict__ bias,
                                               short* __restrict__ xzT)
{
  constexpr int BM = 128, BN = 128, BK = 32;
  __shared__ short As[BM][BK];
  __shared__ short Bs[BK][BN];
  __shared__ short Cs[BM][136];   // +8 pad
  const int tid  = threadIdx.x;
  const int lane = tid & 63, wave = tid >> 6;
  const int wm = (wave >> 1) * 64, wn = (wave & 1) * 64;
  const int fr = lane & 15, kg = lane >> 4;
  const int bm = blockIdx.x * BM, bn = blockIdx.y * BN;

  f32x4 acc[4][4] = {};

  for (int k0 = 0; k0 < D_; k0 += BK) {
    {
      const int r0 = tid >> 3, kq = (tid & 7) * 4;
      #pragma unroll
      for (int it = 0; it < 4; ++it) {
        const int row = r0 + it * 32;
        const float4 v = *reinterpret_cast<const float4*>(&x[(size_t)(bm + row) * D_ + k0 + kq]);
        short4v s; s.x = f2bs(v.x); s.y = f2bs(v.y); s.z = f2bs(v.z); s.w = f2bs(v.w);
        *reinterpret_cast<short4v*>(&As[row][kq]) = s;
      }
    }
    {
      const int kr0 = tid >> 5, nq = (tid & 31) * 4;
      #pragma unroll
      for (int it = 0; it < 4; ++it) {
        const int krow = kr0 + it * 8;
        const float4 v = *reinterpret_cast<const float4*>(&W[(size_t)(k0 + krow) * NG + bn + nq]);
        short4v s; s.x = f2bs(v.x); s.y = f2bs(v.y); s.z = f2bs(v.z); s.w = f2bs(v.w);
        *reinterpret_cast<short4v*>(&Bs[krow][nq]) = s;
      }
    }
    __syncthreads();

    short8 af[4];
    #pragma unroll
    for (int mi = 0; mi < 4; ++mi)
      af[mi] = *reinterpret_cast<const short8*>(&As[wm + mi * 16 + fr][kg * 8]);
    #pragma unroll
    for (int ni = 0; ni < 4; ++ni) {
      short8 bf;
      #pragma unroll
      for (int j = 0; j < 8; ++j) bf[j] = Bs[kg * 8 + j][wn + ni * 16 + fr];
      #pragma unroll
      for (int mi = 0; mi < 4; ++mi)
        acc[mi][ni] = __builtin_amdgcn_mfma_f32_16x16x32_bf16(af[mi], bf, acc[mi][ni], 0, 0, 0);
    }
    __syncthreads();
  }

  // acc -> LDS C-tile (bf16, bias added)
  const int fq = lane >> 4;
  #pragma unroll
  for (int ni = 0; ni < 4; ++ni) {
    const int coln = wn + ni * 16 + fr;
    const float bv = bias[bn + coln];
    #pragma unroll
    for (int mi = 0; mi < 4; ++mi) {
      const int rowb = wm + mi * 16 + fq * 4;
      #pragma unroll
      for (int r = 0; r < 4; ++r)
        Cs[rowb + r][coln] = f2bs(acc[mi][ni][r] + bv);
    }
  }
  __syncthreads();

  // coalesced-ish scatter: 16-col (32B) runs, contiguous in xzT
  const int bb  = bm >> 8;          // batch (const per block)
  const int t0  = bm & 255;         // t base
  const int g   = bn >> 10;         // gate (const per block)
  const int rb0 = (bn & 1023) >> 4; // first recurrence-block index
  #pragma unroll
  for (int it = 0; it < 4; ++it) {
    const int cid  = it * 256 + tid;        // 0..1023
    const int trow = cid >> 3, uu = cid & 7;
    short* dst = xzT + ((size_t)((rb0 + uu) * 256 + (t0 + trow)) * 64 + bb) * 64 + g * 16;
    const short8 v0 = *reinterpret_cast<const short8*>(&Cs[trow][uu * 16]);
    const short8 v1 = *reinterpret_cast<const short8*>(&Cs[trow][uu * 16 + 8]);
    *reinterpret_cast<short8*>(dst)     = v0;
    *reinterpret_cast<short8*>(dst + 8) = v1;
  }
}

// ---------------------------------------------------------------------------
// Persistent recurrence: 64 blocks x 576 thr (8 MFMA waves + 1 signal wave).
// Block owns 16 units (64 gate cols, c = g*16+uj). U bf16 in 128KB LDS.
// Wave (mt = wave&3, kh = wave>>2): h[16b, 512k] loaded ONCE (dup=1) as
// A-frags via counted-vmcnt sc0sc1 loads; 4 n-tiles accumulated per wave;
// 2-way k-reduction through zsm. Signal wave polls 64 flags, publishes
// 4-chunk readiness in LDS go[] (lgkmcnt domain).
// ---------------------------------------------------------------------------
#define H_ISSUE(BUF, O0,O1,O2,O3,O4,O5,O6,O7) \
  asm volatile( \
    "global_load_dwordx4 %0, %8, off offset:" #O0 " sc0 sc1\n\t" \
    "global_load_dwordx4 %1, %8, off offset:" #O1 " sc0 sc1\n\t" \
    "global_load_dwordx4 %2, %8, off offset:" #O2 " sc0 sc1\n\t" \
    "global_load_dwordx4 %3, %8, off offset:" #O3 " sc0 sc1\n\t" \
    "global_load_dwordx4 %4, %8, off offset:" #O4 " sc0 sc1\n\t" \
    "global_load_dwordx4 %5, %8, off offset:" #O5 " sc0 sc1\n\t" \
    "global_load_dwordx4 %6, %8, off offset:" #O6 " sc0 sc1" \
    "\n\tglobal_load_dwordx4 %7, %8, off offset:" #O7 " sc0 sc1" \
    : "=&v"(BUF[0]), "=&v"(BUF[1]), "=&v"(BUF[2]), "=&v"(BUF[3]), \
      "=&v"(BUF[4]), "=&v"(BUF[5]), "=&v"(BUF[6]), "=&v"(BUF[7]) \
    : "v"(hp) : "memory")

#define WAITV(N) do { asm volatile("s_waitcnt vmcnt(" #N ")" ::: "memory"); \
                      __builtin_amdgcn_sched_barrier(0); } while (0)

#define LDSWAIT(C) do { \
    while (__hip_atomic_load(&go[C], __ATOMIC_RELAXED, __HIP_MEMORY_SCOPE_WORKGROUP) < t) \
      __builtin_amdgcn_s_sleep(1); \
    __builtin_amdgcn_sched_barrier(0); \
  } while (0)

// chunk CH (0/1) within this wave's K-half; 4 MFMAs (nt=0..3) per kstep
#define MFMA_CHUNK(BUF, CH) \
  { _Pragma("unroll") \
    for (int i = 0; i < 8; ++i) { \
      const int ksAbs = kh * 16 + (CH) * 8 + i; \
      _Pragma("unroll") \
      for (int nt = 0; nt < 4; ++nt) { \
        const int so = ((ksAbs * 4 + kg) * 64 + nt * 16 + fr) * 8; \
        const short8 bf = *reinterpret_cast<const short8*>(&Us[so]); \
        acc[nt] = __builtin_amdgcn_mfma_f32_16x16x32_bf16(BUF[i], bf, acc[nt], 0, 0, 0); \
      } \
    } }

__global__ __launch_bounds__(576) void lstm_persist(const short* __restrict__ xzT,
                                                    const float* __restrict__ U,
                                                    short* __restrict__ h0buf,
                                                    short* __restrict__ h1buf,
                                                    int* __restrict__ flags,
                                                    float* __restrict__ out)
{
  extern __shared__ char smem[];
  short* Us  = (short*)smem;                   // [k>>3][c][k&7], 128 KiB
  float* zsm = (float*)(smem + 131072);        // [64 b][64 c], 16 KiB
  int*   go  = (int*)(smem + 131072 + 16384);  // [4]

  const int tid  = threadIdx.x;
  const int lane = tid & 63, wave = tid >> 6;
  const int bid  = blockIdx.x;
  const int u0   = bid * 16;
  const int fr = lane & 15, kg = lane >> 4;
  const int mt = wave & 3;        // batch tile (16 rows)
  const int kh = wave >> 2;       // K half (waves 0..7)
  const int gb = tid >> 3, gup = tid & 7;  // gate-math: b, unit-pair (tid<512)

  // Stage U slice once: c = g*16+uj, packed [k>>3][c][k&7] for short8 frags.
  for (int idx = tid; idx < 1024 * 64; idx += 576) {
    const int k = idx >> 6, c = idx & 63;
    const float v = U[(size_t)k * NG + (c >> 4) * NH + u0 + (c & 15)];
    Us[((k >> 3) * 64 + c) * 8 + (k & 7)] = f2bs(v);
  }
  if (tid < 4) go[tid] = 0;
  float creg0 = 0.f, creg1 = 0.f;
  __syncthreads();

  for (int t = 0; t < T_; ++t) {
    const short* __restrict__ hprev = (t & 1) ? h0buf : h1buf;
    short* __restrict__ hnext       = (t & 1) ? h1buf : h0buf;

    // this step's xz: 4 dwords (one per gate), units 2*gup, 2*gup+1
    int xzw[4];
    if (tid < 512) {
      const short* xb = xzT + (((size_t)bid * 256 + t) * 64 + gb) * 64;
      #pragma unroll
      for (int g = 0; g < 4; ++g)
        xzw[g] = *reinterpret_cast<const int*>(xb + g * 16 + 2 * gup);
    }

    f32x4 acc[4] = {};
    if (t > 0) {
      if (wave == 8) {
        // signal wave: poll all 64 flags (lane = producer bid), publish chunks
        const int* fp = flags + lane * 16;
        uint32_t pub = 0;
        while (pub != 0xFu) {
          const int v = __hip_atomic_load(fp, __ATOMIC_RELAXED, __HIP_MEMORY_SCOPE_AGENT);
          const unsigned long long rdy = __ballot(v >= t);
          #pragma unroll
          for (int c = 0; c < 4; ++c) {
            if (!((pub >> c) & 1u) && (((rdy >> (c * 16)) & 0xFFFFull) == 0xFFFFull)) {
              if (lane == (unsigned)(c * 16))
                __hip_atomic_store(&go[c], t, __ATOMIC_RELAXED, __HIP_MEMORY_SCOPE_WORKGROUP);
              pub |= 1u << c;
            }
          }
          if (pub != 0xFu) __builtin_amdgcn_s_sleep(1);
        }
      } else {
        const short* hp = hprev + (size_t)(mt * 16 + fr) * NH + kh * 512 + kg * 8;
        short8 ha[8], hb[8];
        LDSWAIT(2 * kh);     H_ISSUE(ha, 0, 64, 128, 192, 256, 320, 384, 448);
        LDSWAIT(2 * kh + 1); H_ISSUE(hb, 512, 576, 640, 704, 768, 832, 896, 960);
        WAITV(8);  MFMA_CHUNK(ha, 0);
        WAITV(0);  MFMA_CHUNK(hb, 1);
        if (kh == 1) {
          #pragma unroll
          for (int nt = 0; nt < 4; ++nt)
            #pragma unroll
            for (int r = 0; r < 4; ++r)
              zsm[(mt * 16 + kg * 4 + r) * 64 + nt * 16 + fr] = acc[nt][r];
        }
      }
      __syncthreads();   // S1: kh=1 partials visible
      if (wave < 8 && kh == 0) {
        #pragma unroll
        for (int nt = 0; nt < 4; ++nt)
          #pragma unroll
          for (int r = 0; r < 4; ++r) {
            const int zi = (mt * 16 + kg * 4 + r) * 64 + nt * 16 + fr;
            zsm[zi] += acc[nt][r];
          }
      }
      __syncthreads();   // S2: final z visible
    }

    float hh0 = 0.f, hh1 = 0.f;
    if (tid < 512) {  // gate math: b = gb, units u0+2*gup, u0+2*gup+1
      float z[4][2];
      #pragma unroll
      for (int g = 0; g < 4; ++g) {
        z[g][0] = bs2f((short)(xzw[g] & 0xFFFF));
        z[g][1] = bs2f((short)(((uint32_t)xzw[g]) >> 16));
        if (t > 0) {
          const float2 zz = *reinterpret_cast<const float2*>(&zsm[gb * 64 + g * 16 + 2 * gup]);
          z[g][0] += zz.x; z[g][1] += zz.y;
        }
      }
      {
        const float ig = fsigm(z[0][0]), fg = fsigm(z[1][0]);
        const float gg = ftanh(z[2][0]), og = fsigm(z[3][0]);
        creg0 = fg * creg0 + ig * gg;  hh0 = og * ftanh(creg0);
      }
      {
        const float ig = fsigm(z[0][1]), fg = fsigm(z[1][1]);
        const float gg = ftanh(z[2][1]), og = fsigm(z[3][1]);
        creg1 = fg * creg1 + ig * gg;  hh1 = og * ftanh(creg1);
      }
      if (t < T_ - 1) {
        const uint32_t word = (uint32_t)(uint16_t)f2bs(hh0) | ((uint32_t)(uint16_t)f2bs(hh1) << 16);
        uint32_t* hp32 = (uint32_t*)(hnext + (size_t)gb * NH + u0 + 2 * gup);
        asm volatile("global_store_dword %0, %1, off sc0 sc1" :: "v"(hp32), "v"(word) : "memory");
      }
    }
    if (t < T_ - 1) WAITV(0);   // drain h stores (per-wave)
    __syncthreads();            // S3: whole block's h globally visible

    if (t < T_ - 1 && tid == 0)
      __hip_atomic_store(&flags[bid * 16], t + 1, __ATOMIC_RELAXED, __HIP_MEMORY_SCOPE_AGENT);

    if (tid < 512) {  // out store off the critical path
      float2 o; o.x = hh0; o.y = hh1;
      *reinterpret_cast<float2*>(&out[((size_t)gb * T_ + t) * NH + u0 + 2 * gup]) = o;
    }
  }
}

extern "C" void kernel_launch(void* const* d_in, const int* in_sizes, int n_in,
                              void* d_out, int out_size, void* d_ws, size_t ws_size,
                              hipStream_t stream) {
  const float* x    = (const float*)d_in[0];
  const float* W    = (const float*)d_in[1];
  const float* U    = (const float*)d_in[2];
  const float* bias = (const float*)d_in[3];
  float* out = (float*)d_out;
  char* ws = (char*)d_ws;

  // ws: xzT bf16 128 MiB | flags 8 KiB | h ping/pong 2 x 128 KiB
  short* xzT   = (short*)ws;
  int*   flags = (int*)(ws + 134217728);
  short* hA    = (short*)(ws + 134225920);
  short* hB    = (short*)(ws + 134356992);

  hipMemsetAsync(flags, 0, 8192, stream);  // 0 = "no h visible yet"
  xz_gemm<<<dim3(128, 32), 256, 0, stream>>>(x, W, bias, xzT);

  hipFuncSetAttribute((const void*)lstm_persist,
                      hipFuncAttributeMaxDynamicSharedMemorySize, LDS_BYTES);
  lstm_persist<<<dim3(NBLK), dim3(576), LDS_BYTES, stream>>>(xzT, U, hA, hB, flags, out);
}